// Round 1
// baseline (485.181 us; speedup 1.0000x reference)
//
#include <hip/hip_runtime.h>
#include <stdint.h>

// Problem constants
#define B_ 4
#define T_ 2048
#define C_ 1024
#define H_ 16
#define D_ 64
#define M_ (B_*T_)   // 8192 rows in the projection GEMMs

typedef float f4 __attribute__((ext_vector_type(4)));
typedef float f32x4 __attribute__((ext_vector_type(4)));
typedef __bf16 bf16x8 __attribute__((ext_vector_type(8)));
typedef unsigned short u16x4 __attribute__((ext_vector_type(4)));

__device__ __forceinline__ unsigned short f2bf(float f) {
  unsigned u = __builtin_bit_cast(unsigned, f);
  u += 0x7fffu + ((u >> 16) & 1u);   // RNE
  return (unsigned short)(u >> 16);
}

__device__ __forceinline__ f4 mfma16(bf16x8 a, bf16x8 b, f4 c) {
  return __builtin_amdgcn_mfma_f32_16x16x32_bf16(a, b, c, 0, 0, 0);
}

__device__ __forceinline__ void gload16(const void* g, void* l) {
  __builtin_amdgcn_global_load_lds(
      (const __attribute__((address_space(1))) unsigned int*)g,
      (__attribute__((address_space(3))) unsigned int*)l, 16, 0, 0);
}

// ---------------- RoPE tables: cos/sin/scale/iscale, each [T][D] f32 -------
__global__ void prep_tables(float* __restrict__ cosT, float* __restrict__ sinT,
                            float* __restrict__ scT, float* __restrict__ iscT) {
  int idx = blockIdx.x * blockDim.x + threadIdx.x;   // T * D/2 = 65536
  if (idx >= T_ * (D_ / 2)) return;
  int t = idx >> 5;          // D/2 = 32
  int i = idx & 31;          // pair index
  float d2 = 2.0f * (float)i;
  float inv_freq = powf(10000.0f, -(d2 / 64.0f));
  float fr = (float)t * inv_freq;
  float c = cosf(fr), s = sinf(fr);
  float base = (d2 + 0.4f * 64.0f) / (1.4f * 64.0f);
  float pw = ((float)t - 1024.0f) / 512.0f;
  float sc = powf(base, pw);
  int o = t * 64 + i * 2;
  cosT[o] = c; cosT[o + 1] = c;
  sinT[o] = s; sinT[o + 1] = s;
  scT[o] = sc; scT[o + 1] = sc;
  iscT[o] = 1.0f / sc; iscT[o + 1] = 1.0f / sc;
}

// ---------------- f32 -> bf16 conversion ----------------------------------
__global__ void cvt_bf16(const float* __restrict__ src,
                         unsigned short* __restrict__ dst, int n4) {
  int i = blockIdx.x * blockDim.x + threadIdx.x;
  if (i >= n4) return;
  f32x4 v = *(const f32x4*)(src + (size_t)i * 4);
  u16x4 o;
  o[0] = f2bf(v[0]); o[1] = f2bf(v[1]); o[2] = f2bf(v[2]); o[3] = f2bf(v[3]);
  *(u16x4*)(dst + (size_t)i * 4) = o;
}

// ---------------- NT GEMM: out[r][n] = sum_k A[r][k] * W[n][k] ------------
// MODE 0: Q  -> rope * scale,  bf16 out [B][H][T][D]
// MODE 1: K  -> rope * iscale, bf16 out [B][H][T][D]
// MODE 2: V  -> bf16 out transposed [B][H][D][T]
// MODE 3: O  -> f32 out [r][n]
template <int MODE>
__global__ __launch_bounds__(256, 2)
void gemm_nt(const unsigned short* __restrict__ A,
             const unsigned short* __restrict__ W,
             void* __restrict__ outp,
             const float* __restrict__ cosT,
             const float* __restrict__ sinT,
             const float* __restrict__ scT) {
  __shared__ __align__(16) unsigned short As[128 * 32];
  __shared__ __align__(16) unsigned short Bs[128 * 32];

  const int tid = threadIdx.x;
  const int lane = tid & 63;
  const int wave = tid >> 6;
  const int m0 = blockIdx.y * 128;
  const int n0 = blockIdx.x * 128;
  const int wm = (wave >> 1) * 64;
  const int wn = (wave & 1) * 64;
  const int fr = lane & 15;
  const int fg = lane >> 4;          // k-group 0..3

  f4 acc[4][4];
#pragma unroll
  for (int mi = 0; mi < 4; ++mi)
#pragma unroll
    for (int ni = 0; ni < 4; ++ni) acc[mi][ni] = (f4){0.f, 0.f, 0.f, 0.f};

  // staging: chunk = 1KB = 16 rows x 32 cols bf16. 8 chunks, 2 per wave.
  // lane i -> row i>>2, 16B slot (i&3), source-swizzled by (row&3)
  const int c0 = wave * 2, c1 = wave * 2 + 1;
  const int srow = lane >> 2;
  const int sslot = (lane & 3) ^ (srow & 3);
  const unsigned short* a0 = A + (size_t)(m0 + c0 * 16 + srow) * 1024 + sslot * 8;
  const unsigned short* a1 = A + (size_t)(m0 + c1 * 16 + srow) * 1024 + sslot * 8;
  const unsigned short* b0 = W + (size_t)(n0 + c0 * 16 + srow) * 1024 + sslot * 8;
  const unsigned short* b1 = W + (size_t)(n0 + c1 * 16 + srow) * 1024 + sslot * 8;
  unsigned short* la0 = &As[c0 * 512];
  unsigned short* la1 = &As[c1 * 512];
  unsigned short* lb0 = &Bs[c0 * 512];
  unsigned short* lb1 = &Bs[c1 * 512];

  for (int k0 = 0; k0 < 1024; k0 += 32) {
    __syncthreads();
    gload16(a0 + k0, la0);
    gload16(a1 + k0, la1);
    gload16(b0 + k0, lb0);
    gload16(b1 + k0, lb1);
    asm volatile("s_waitcnt vmcnt(0)" ::: "memory");
    __syncthreads();

    bf16x8 af[4], bfr[4];
#pragma unroll
    for (int mi = 0; mi < 4; ++mi) {
      int row = wm + mi * 16 + fr;
      af[mi] = *(const bf16x8*)&As[row * 32 + ((fg ^ (fr & 3)) * 8)];
    }
#pragma unroll
    for (int ni = 0; ni < 4; ++ni) {
      int row = wn + ni * 16 + fr;
      bfr[ni] = *(const bf16x8*)&Bs[row * 32 + ((fg ^ (fr & 3)) * 8)];
    }
#pragma unroll
    for (int mi = 0; mi < 4; ++mi)
#pragma unroll
      for (int ni = 0; ni < 4; ++ni)
        acc[mi][ni] = mfma16(af[mi], bfr[ni], acc[mi][ni]);
  }

  const int frow = (lane >> 4) * 4;

  if constexpr (MODE == 3) {
    float* O = (float*)outp;
#pragma unroll
    for (int mi = 0; mi < 4; ++mi)
#pragma unroll
      for (int ni = 0; ni < 4; ++ni) {
        int n = n0 + wn + ni * 16 + fr;
#pragma unroll
        for (int i = 0; i < 4; ++i) {
          int r = m0 + wm + mi * 16 + frow + i;
          O[(size_t)r * 1024 + n] = acc[mi][ni][i];
        }
      }
  } else if constexpr (MODE == 2) {
    unsigned short* Vt = (unsigned short*)outp;
#pragma unroll
    for (int mi = 0; mi < 4; ++mi) {
      int r0 = m0 + wm + mi * 16 + frow;
      int b = r0 >> 11, t0v = r0 & 2047;   // t0v % 4 == 0, never crosses batch
#pragma unroll
      for (int ni = 0; ni < 4; ++ni) {
        int n = n0 + wn + ni * 16 + fr;
        size_t base = ((size_t)(b * 16 + (n >> 6)) * 64 + (n & 63)) * 2048 + t0v;
        u16x4 pk;
        pk[0] = f2bf(acc[mi][ni][0]);
        pk[1] = f2bf(acc[mi][ni][1]);
        pk[2] = f2bf(acc[mi][ni][2]);
        pk[3] = f2bf(acc[mi][ni][3]);
        *(u16x4*)&Vt[base] = pk;
      }
    }
  } else {
    unsigned short* O = (unsigned short*)outp;
#pragma unroll
    for (int mi = 0; mi < 4; ++mi)
#pragma unroll
      for (int ni = 0; ni < 4; ++ni) {
        int n = n0 + wn + ni * 16 + fr;
        int d = n & 63, h = n >> 6;
#pragma unroll
        for (int i = 0; i < 4; ++i) {
          int r = m0 + wm + mi * 16 + frow + i;
          int t = r & 2047, b = r >> 11;
          float v = acc[mi][ni][i];
          float p = __shfl_xor(v, 1);       // partner element of the rope pair
          int o = t * 64 + d;
          float cv = cosT[o], sv = sinT[o], scv = scT[o];
          float rot = (d & 1) ? p : -p;     // rotate_half
          float res = (v * cv + rot * sv) * scv;
          O[((size_t)(b * 16 + h) * 2048 + t) * 64 + d] = f2bf(res);
        }
      }
  }
}

// ---------------- flash attention --------------------------------------
// grid: B*H*(T/64) blocks; 4 waves, each owns 16 q-rows. KVBLK=64.
__global__ __launch_bounds__(256, 2)
void attn_fwd(const unsigned short* __restrict__ Q,
              const unsigned short* __restrict__ K,
              const unsigned short* __restrict__ Vt,
              const int* __restrict__ mask,
              unsigned short* __restrict__ Oa) {
  __shared__ __align__(16) unsigned short Ks[64 * 64];
  __shared__ __align__(16) unsigned short Vs[64 * 64];
  __shared__ __align__(16) unsigned short Ps[4][16][80];  // per-wave P, padded

  const int bid = blockIdx.x;
  const int qt = bid & 31;
  const int h = (bid >> 5) & 15;
  const int b = bid >> 9;
  const int tid = threadIdx.x;
  const int lane = tid & 63;
  const int wave = tid >> 6;
  const int fr = lane & 15;
  const int fg = lane >> 4;
  const int frow = fg * 4;

  const unsigned short* Qb = Q + (size_t)(b * 16 + h) * 2048 * 64;
  const unsigned short* Kb = K + (size_t)(b * 16 + h) * 2048 * 64;
  const unsigned short* Vb = Vt + (size_t)(b * 16 + h) * 64 * 2048;
  const int* Mb = mask + (size_t)b * 2048 * 2048;

  const int q0 = qt * 64 + wave * 16;

  // Q fragments held in registers for the whole kernel
  bf16x8 qf0 = *(const bf16x8*)&Qb[(q0 + fr) * 64 + fg * 8];
  bf16x8 qf1 = *(const bf16x8*)&Qb[(q0 + fr) * 64 + 32 + fg * 8];

  f4 po[4];
#pragma unroll
  for (int nd = 0; nd < 4; ++nd) po[nd] = (f4){0.f, 0.f, 0.f, 0.f};
  float mr[4] = {-INFINITY, -INFINITY, -INFINITY, -INFINITY};
  float lr[4] = {0.f, 0.f, 0.f, 0.f};

  // staging: K tile rows are 128B; chunk = 1KB = 8 rows. XOR-swizzled source.
  const int c0 = wave * 2, c1 = wave * 2 + 1;
  const int krow0 = lane >> 3;                   // 0..7 row within chunk
  const int kslot = (lane & 7) ^ (krow0 & 7);    // swizzled 16B slot
  const unsigned short* kg0 = Kb + (size_t)(c0 * 8 + krow0) * 64 + kslot * 8;
  const unsigned short* kg1 = Kb + (size_t)(c1 * 8 + krow0) * 64 + kslot * 8;
  const unsigned short* vg0 = Vb + (size_t)(c0 * 8 + krow0) * 2048 + kslot * 8;
  const unsigned short* vg1 = Vb + (size_t)(c1 * 8 + krow0) * 2048 + kslot * 8;
  unsigned short* lk0 = &Ks[c0 * 512];
  unsigned short* lk1 = &Ks[c1 * 512];
  unsigned short* lv0 = &Vs[c0 * 512];
  unsigned short* lv1 = &Vs[c1 * 512];

  for (int kt = 0; kt < 32; ++kt) {
    __syncthreads();
    gload16(kg0 + (size_t)kt * 4096, lk0);
    gload16(kg1 + (size_t)kt * 4096, lk1);
    gload16(vg0 + kt * 64, lv0);
    gload16(vg1 + kt * 64, lv1);
    asm volatile("s_waitcnt vmcnt(0)" ::: "memory");
    __syncthreads();

    // S = Q K^T  (per wave: 16 x 64)
    f4 sf[4];
#pragma unroll
    for (int nf = 0; nf < 4; ++nf) {
      int krow = nf * 16 + fr;
      int sw = krow & 7;
      bf16x8 kf0 = *(const bf16x8*)&Ks[krow * 64 + ((fg ^ sw) * 8)];
      bf16x8 kf1 = *(const bf16x8*)&Ks[krow * 64 + (((4 + fg) ^ sw) * 8)];
      f4 a = (f4){0.f, 0.f, 0.f, 0.f};
      a = mfma16(qf0, kf0, a);
      a = mfma16(qf1, kf1, a);
      sf[nf] = a;
    }

    // scale + mask
    const int kb = kt * 64;
#pragma unroll
    for (int nf = 0; nf < 4; ++nf) {
      int kc = kb + nf * 16 + fr;
#pragma unroll
      for (int i = 0; i < 4; ++i) {
        int qr = q0 + frow + i;
        float sv = sf[nf][i] * 0.03125f;   // 1/sqrt(C) = 1/32
        sf[nf][i] = (Mb[(size_t)qr * 2048 + kc] != 0) ? sv : -10000.0f;
      }
    }

    // wave-parallel row max (rows live across 16 lanes of each lane-group)
    float tm[4];
#pragma unroll
    for (int i = 0; i < 4; ++i)
      tm[i] = fmaxf(fmaxf(sf[0][i], sf[1][i]), fmaxf(sf[2][i], sf[3][i]));
#pragma unroll
    for (int s = 1; s < 16; s <<= 1)
#pragma unroll
      for (int i = 0; i < 4; ++i) tm[i] = fmaxf(tm[i], __shfl_xor(tm[i], s));

    float corr[4];
#pragma unroll
    for (int i = 0; i < 4; ++i) {
      float mn = fmaxf(mr[i], tm[i]);
      corr[i] = __expf(mr[i] - mn);
      mr[i] = mn;
    }
    float ls[4] = {0.f, 0.f, 0.f, 0.f};
#pragma unroll
    for (int nf = 0; nf < 4; ++nf)
#pragma unroll
      for (int i = 0; i < 4; ++i) {
        float p = __expf(sf[nf][i] - mr[i]);
        sf[nf][i] = p;
        ls[i] += p;
      }
#pragma unroll
    for (int s = 1; s < 16; s <<= 1)
#pragma unroll
      for (int i = 0; i < 4; ++i) ls[i] += __shfl_xor(ls[i], s);
#pragma unroll
    for (int i = 0; i < 4; ++i) lr[i] = lr[i] * corr[i] + ls[i];
#pragma unroll
    for (int nd = 0; nd < 4; ++nd)
#pragma unroll
      for (int i = 0; i < 4; ++i) po[nd][i] *= corr[i];

    // P -> LDS (bf16), re-read in A-fragment layout (wave-local, HW in-order)
#pragma unroll
    for (int nf = 0; nf < 4; ++nf)
#pragma unroll
      for (int i = 0; i < 4; ++i)
        Ps[wave][frow + i][nf * 16 + fr] = f2bf(sf[nf][i]);

    bf16x8 pf0 = *(const bf16x8*)&Ps[wave][fr][fg * 8];
    bf16x8 pf1 = *(const bf16x8*)&Ps[wave][fr][32 + fg * 8];

#pragma unroll
    for (int nd = 0; nd < 4; ++nd) {
      int vrow = nd * 16 + fr;
      int sw = vrow & 7;
      bf16x8 vf0 = *(const bf16x8*)&Vs[vrow * 64 + ((fg ^ sw) * 8)];
      bf16x8 vf1 = *(const bf16x8*)&Vs[vrow * 64 + (((4 + fg) ^ sw) * 8)];
      po[nd] = mfma16(pf0, vf0, po[nd]);
      po[nd] = mfma16(pf1, vf1, po[nd]);
    }
  }

  // epilogue: out[b][t][h*64+d] bf16
#pragma unroll
  for (int nd = 0; nd < 4; ++nd) {
    int col = h * 64 + nd * 16 + fr;
#pragma unroll
    for (int i = 0; i < 4; ++i) {
      int r = b * 2048 + q0 + frow + i;
      float o = po[nd][i] / lr[i];
      Oa[(size_t)r * 1024 + col] = f2bf(o);
    }
  }
}

// ---------------------------------------------------------------------------
extern "C" void kernel_launch(void* const* d_in, const int* in_sizes, int n_in,
                              void* d_out, int out_size, void* d_ws, size_t ws_size,
                              hipStream_t stream) {
  const float* x = (const float*)d_in[0];
  const int* mask = (const int*)d_in[1];
  const float* Wq = (const float*)d_in[2];
  const float* Wk = (const float*)d_in[3];
  const float* Wv = (const float*)d_in[4];
  const float* Wo = (const float*)d_in[5];
  float* out = (float*)d_out;
  char* ws = (char*)d_ws;

  float* cosT = (float*)(ws + 0x0);
  float* sinT = (float*)(ws + 0x80000);
  float* scT  = (float*)(ws + 0x100000);
  float* iscT = (float*)(ws + 0x180000);
  unsigned short* xb  = (unsigned short*)(ws + 0x200000);   // 16MB
  unsigned short* wqb = (unsigned short*)(ws + 0x1200000);  // 2MB each
  unsigned short* wkb = (unsigned short*)(ws + 0x1400000);
  unsigned short* wvb = (unsigned short*)(ws + 0x1600000);
  unsigned short* wob = (unsigned short*)(ws + 0x1800000);
  unsigned short* Qb  = (unsigned short*)(ws + 0x1A00000);  // 16MB each
  unsigned short* Kb  = (unsigned short*)(ws + 0x2A00000);
  unsigned short* Vtb = (unsigned short*)(ws + 0x3A00000);
  unsigned short* Aob = (unsigned short*)(ws + 0x4A00000);  // ends 0x5A00000

  prep_tables<<<(T_ * (D_ / 2) + 255) / 256, 256, 0, stream>>>(cosT, sinT, scT, iscT);
  cvt_bf16<<<(M_ * C_ / 4 + 255) / 256, 256, 0, stream>>>(x, xb, M_ * C_ / 4);
  cvt_bf16<<<(C_ * C_ / 4 + 255) / 256, 256, 0, stream>>>(Wq, wqb, C_ * C_ / 4);
  cvt_bf16<<<(C_ * C_ / 4 + 255) / 256, 256, 0, stream>>>(Wk, wkb, C_ * C_ / 4);
  cvt_bf16<<<(C_ * C_ / 4 + 255) / 256, 256, 0, stream>>>(Wv, wvb, C_ * C_ / 4);
  cvt_bf16<<<(C_ * C_ / 4 + 255) / 256, 256, 0, stream>>>(Wo, wob, C_ * C_ / 4);

  dim3 g(C_ / 128, M_ / 128);   // (8, 64)
  gemm_nt<0><<<g, 256, 0, stream>>>(xb, wqb, Qb, cosT, sinT, scT);
  gemm_nt<1><<<g, 256, 0, stream>>>(xb, wkb, Kb, cosT, sinT, iscT);
  gemm_nt<2><<<g, 256, 0, stream>>>(xb, wvb, Vtb, nullptr, nullptr, nullptr);

  attn_fwd<<<B_ * H_ * (T_ / 64), 256, 0, stream>>>(Qb, Kb, Vtb, mask, Aob);

  gemm_nt<3><<<g, 256, 0, stream>>>(Aob, wob, out, nullptr, nullptr, nullptr);
}

// Round 4
// 470.746 us; speedup vs baseline: 1.0307x; 1.0307x over previous
//
#include <hip/hip_runtime.h>
#include <stdint.h>

// Problem constants
#define B_ 4
#define T_ 2048
#define C_ 1024
#define H_ 16
#define D_ 64
#define M_ (B_*T_)   // 8192 rows in the projection GEMMs

typedef float f4 __attribute__((ext_vector_type(4)));
typedef float f32x4 __attribute__((ext_vector_type(4)));
typedef __bf16 bf16x8 __attribute__((ext_vector_type(8)));
typedef __bf16 bf16x4 __attribute__((ext_vector_type(4)));
typedef unsigned short u16x4 __attribute__((ext_vector_type(4)));
typedef int i32x4 __attribute__((ext_vector_type(4)));

__device__ __forceinline__ unsigned short f2bf(float f) {
  unsigned u = __builtin_bit_cast(unsigned, f);
  u += 0x7fffu + ((u >> 16) & 1u);   // RNE
  return (unsigned short)(u >> 16);
}

__device__ __forceinline__ f4 mfma16(bf16x8 a, bf16x8 b, f4 c) {
  return __builtin_amdgcn_mfma_f32_16x16x32_bf16(a, b, c, 0, 0, 0);
}

__device__ __forceinline__ void gload16(const void* g, void* l) {
  __builtin_amdgcn_global_load_lds(
      (const __attribute__((address_space(1))) unsigned int*)g,
      (__attribute__((address_space(3))) unsigned int*)l, 16, 0, 0);
}

// ---------------- RoPE tables: cos/sin/scale/iscale, each [T][D] f32 -------
__global__ void prep_tables(float* __restrict__ cosT, float* __restrict__ sinT,
                            float* __restrict__ scT, float* __restrict__ iscT) {
  int idx = blockIdx.x * blockDim.x + threadIdx.x;   // T * D/2 = 65536
  if (idx >= T_ * (D_ / 2)) return;
  int t = idx >> 5;          // D/2 = 32
  int i = idx & 31;          // pair index
  float d2 = 2.0f * (float)i;
  float inv_freq = powf(10000.0f, -(d2 / 64.0f));
  float fr = (float)t * inv_freq;
  float c = cosf(fr), s = sinf(fr);
  float base = (d2 + 0.4f * 64.0f) / (1.4f * 64.0f);
  float pw = ((float)t - 1024.0f) / 512.0f;
  float sc = powf(base, pw);
  int o = t * 64 + i * 2;
  cosT[o] = c; cosT[o + 1] = c;
  sinT[o] = s; sinT[o + 1] = s;
  scT[o] = sc; scT[o + 1] = sc;
  iscT[o] = 1.0f / sc; iscT[o + 1] = 1.0f / sc;
}

// ---------------- f32 -> bf16 conversion ----------------------------------
__global__ void cvt_bf16(const float* __restrict__ src,
                         unsigned short* __restrict__ dst, int n4) {
  int i = blockIdx.x * blockDim.x + threadIdx.x;
  if (i >= n4) return;
  f32x4 v = *(const f32x4*)(src + (size_t)i * 4);
  u16x4 o;
  o[0] = f2bf(v[0]); o[1] = f2bf(v[1]); o[2] = f2bf(v[2]); o[3] = f2bf(v[3]);
  *(u16x4*)(dst + (size_t)i * 4) = o;
}

// ---------------- fused QKV GEMM: out[r][n] = sum_k A[r][k] * W[n][k] ------
// blockIdx.z: 0=Q (rope*scale), 1=K (rope/scale), 2=V (transposed store)
__global__ __launch_bounds__(256, 2)
void gemm_qkv(const unsigned short* __restrict__ A,
              const unsigned short* __restrict__ Wq,
              const unsigned short* __restrict__ Wk,
              const unsigned short* __restrict__ Wv,
              unsigned short* __restrict__ Qo,
              unsigned short* __restrict__ Ko,
              unsigned short* __restrict__ Vo,
              const float* __restrict__ cosT,
              const float* __restrict__ sinT,
              const float* __restrict__ scT,
              const float* __restrict__ iscT) {
  __shared__ __align__(16) unsigned short As[2][128 * 32];
  __shared__ __align__(16) unsigned short Bs[2][128 * 32];

  const int z = blockIdx.z;
  const unsigned short* W = (z == 0) ? Wq : (z == 1) ? Wk : Wv;

  const int tid = threadIdx.x;
  const int lane = tid & 63;
  const int wave = tid >> 6;
  const int m0 = blockIdx.y * 128;
  const int n0 = blockIdx.x * 128;
  const int wm = (wave >> 1) * 64;
  const int wn = (wave & 1) * 64;
  const int fr = lane & 15;
  const int fg = lane >> 4;

  f4 acc[4][4];
#pragma unroll
  for (int mi = 0; mi < 4; ++mi)
#pragma unroll
    for (int ni = 0; ni < 4; ++ni) acc[mi][ni] = (f4){0.f, 0.f, 0.f, 0.f};

  const int c0 = wave * 2, c1 = wave * 2 + 1;
  const int srow = lane >> 2;
  const int sslot = (lane & 3) ^ (srow & 3);
  const unsigned short* a0 = A + (size_t)(m0 + c0 * 16 + srow) * 1024 + sslot * 8;
  const unsigned short* a1 = A + (size_t)(m0 + c1 * 16 + srow) * 1024 + sslot * 8;
  const unsigned short* b0 = W + (size_t)(n0 + c0 * 16 + srow) * 1024 + sslot * 8;
  const unsigned short* b1 = W + (size_t)(n0 + c1 * 16 + srow) * 1024 + sslot * 8;

  // prologue: stage k0=0 into buffer 0
  gload16(a0, &As[0][c0 * 512]);
  gload16(a1, &As[0][c1 * 512]);
  gload16(b0, &Bs[0][c0 * 512]);
  gload16(b1, &Bs[0][c1 * 512]);
  asm volatile("s_waitcnt vmcnt(0)" ::: "memory");
  __builtin_amdgcn_s_barrier();

  for (int k0 = 0; k0 < 1024; k0 += 32) {
    const int cur = (k0 >> 5) & 1;
    if (k0 + 32 < 1024) {
      const int nxt = cur ^ 1;
      gload16(a0 + k0 + 32, &As[nxt][c0 * 512]);
      gload16(a1 + k0 + 32, &As[nxt][c1 * 512]);
      gload16(b0 + k0 + 32, &Bs[nxt][c0 * 512]);
      gload16(b1 + k0 + 32, &Bs[nxt][c1 * 512]);
    }
    bf16x8 af[4], bfr[4];
#pragma unroll
    for (int mi = 0; mi < 4; ++mi) {
      int row = wm + mi * 16 + fr;
      af[mi] = *(const bf16x8*)&As[cur][row * 32 + ((fg ^ (fr & 3)) * 8)];
    }
#pragma unroll
    for (int ni = 0; ni < 4; ++ni) {
      int row = wn + ni * 16 + fr;
      bfr[ni] = *(const bf16x8*)&Bs[cur][row * 32 + ((fg ^ (fr & 3)) * 8)];
    }
#pragma unroll
    for (int mi = 0; mi < 4; ++mi)
#pragma unroll
      for (int ni = 0; ni < 4; ++ni)
        acc[mi][ni] = mfma16(af[mi], bfr[ni], acc[mi][ni]);
    asm volatile("s_waitcnt vmcnt(0)" ::: "memory");
    __builtin_amdgcn_s_barrier();
  }

  const int frow = fg * 4;

  if (z == 2) {
    // V: store transposed [B][H][D][T]
#pragma unroll
    for (int mi = 0; mi < 4; ++mi) {
      int r0 = m0 + wm + mi * 16 + frow;
      int b = r0 >> 11, t0v = r0 & 2047;
#pragma unroll
      for (int ni = 0; ni < 4; ++ni) {
        int n = n0 + wn + ni * 16 + fr;
        size_t base = ((size_t)(b * 16 + (n >> 6)) * 64 + (n & 63)) * 2048 + t0v;
        u16x4 pk;
        pk[0] = f2bf(acc[mi][ni][0]);
        pk[1] = f2bf(acc[mi][ni][1]);
        pk[2] = f2bf(acc[mi][ni][2]);
        pk[3] = f2bf(acc[mi][ni][3]);
        *(u16x4*)&Vo[base] = pk;
      }
    }
  } else {
    unsigned short* O = (z == 0) ? Qo : Ko;
    const float* sT = (z == 0) ? scT : iscT;
#pragma unroll
    for (int mi = 0; mi < 4; ++mi)
#pragma unroll
      for (int ni = 0; ni < 4; ++ni) {
        int n = n0 + wn + ni * 16 + fr;
        int d = n & 63, hh = n >> 6;
#pragma unroll
        for (int i = 0; i < 4; ++i) {
          int r = m0 + wm + mi * 16 + frow + i;
          int t = r & 2047, b = r >> 11;
          float v = acc[mi][ni][i];
          float p = __shfl_xor(v, 1);
          int o = t * 64 + d;
          float cv = cosT[o], sv = sinT[o], scv = sT[o];
          float rot = (d & 1) ? p : -p;
          float res = (v * cv + rot * sv) * scv;
          O[((size_t)(b * 16 + hh) * 2048 + t) * 64 + d] = f2bf(res);
        }
      }
  }
}

// ---------------- output GEMM (f32 out) ------------------------------------
__global__ __launch_bounds__(256, 2)
void gemm_out(const unsigned short* __restrict__ A,
              const unsigned short* __restrict__ W,
              float* __restrict__ O) {
  __shared__ __align__(16) unsigned short As[2][128 * 32];
  __shared__ __align__(16) unsigned short Bs[2][128 * 32];

  const int tid = threadIdx.x;
  const int lane = tid & 63;
  const int wave = tid >> 6;
  const int m0 = blockIdx.y * 128;
  const int n0 = blockIdx.x * 128;
  const int wm = (wave >> 1) * 64;
  const int wn = (wave & 1) * 64;
  const int fr = lane & 15;
  const int fg = lane >> 4;

  f4 acc[4][4];
#pragma unroll
  for (int mi = 0; mi < 4; ++mi)
#pragma unroll
    for (int ni = 0; ni < 4; ++ni) acc[mi][ni] = (f4){0.f, 0.f, 0.f, 0.f};

  const int c0 = wave * 2, c1 = wave * 2 + 1;
  const int srow = lane >> 2;
  const int sslot = (lane & 3) ^ (srow & 3);
  const unsigned short* a0 = A + (size_t)(m0 + c0 * 16 + srow) * 1024 + sslot * 8;
  const unsigned short* a1 = A + (size_t)(m0 + c1 * 16 + srow) * 1024 + sslot * 8;
  const unsigned short* b0 = W + (size_t)(n0 + c0 * 16 + srow) * 1024 + sslot * 8;
  const unsigned short* b1 = W + (size_t)(n0 + c1 * 16 + srow) * 1024 + sslot * 8;

  gload16(a0, &As[0][c0 * 512]);
  gload16(a1, &As[0][c1 * 512]);
  gload16(b0, &Bs[0][c0 * 512]);
  gload16(b1, &Bs[0][c1 * 512]);
  asm volatile("s_waitcnt vmcnt(0)" ::: "memory");
  __builtin_amdgcn_s_barrier();

  for (int k0 = 0; k0 < 1024; k0 += 32) {
    const int cur = (k0 >> 5) & 1;
    if (k0 + 32 < 1024) {
      const int nxt = cur ^ 1;
      gload16(a0 + k0 + 32, &As[nxt][c0 * 512]);
      gload16(a1 + k0 + 32, &As[nxt][c1 * 512]);
      gload16(b0 + k0 + 32, &Bs[nxt][c0 * 512]);
      gload16(b1 + k0 + 32, &Bs[nxt][c1 * 512]);
    }
    bf16x8 af[4], bfr[4];
#pragma unroll
    for (int mi = 0; mi < 4; ++mi) {
      int row = wm + mi * 16 + fr;
      af[mi] = *(const bf16x8*)&As[cur][row * 32 + ((fg ^ (fr & 3)) * 8)];
    }
#pragma unroll
    for (int ni = 0; ni < 4; ++ni) {
      int row = wn + ni * 16 + fr;
      bfr[ni] = *(const bf16x8*)&Bs[cur][row * 32 + ((fg ^ (fr & 3)) * 8)];
    }
#pragma unroll
    for (int mi = 0; mi < 4; ++mi)
#pragma unroll
      for (int ni = 0; ni < 4; ++ni)
        acc[mi][ni] = mfma16(af[mi], bfr[ni], acc[mi][ni]);
    asm volatile("s_waitcnt vmcnt(0)" ::: "memory");
    __builtin_amdgcn_s_barrier();
  }

  const int frow = fg * 4;
#pragma unroll
  for (int mi = 0; mi < 4; ++mi)
#pragma unroll
    for (int ni = 0; ni < 4; ++ni) {
      int n = n0 + wn + ni * 16 + fr;
#pragma unroll
      for (int i = 0; i < 4; ++i) {
        int r = m0 + wm + mi * 16 + frow + i;
        O[(size_t)r * 1024 + n] = acc[mi][ni][i];
      }
    }
}

// ---------------- flash attention (swapped-QK^T layout) --------------------
// grid: B*H*(T/64) blocks (XCD-swizzled); 4 waves x 16 q-rows. KVBLK=64.
// S^T = mfma(K_frag, Q_frag): lane holds S[q=lane&15][k = nf*16 + fg*4 + i]
// -> k-contiguous regs: vector mask loads, lane-local row reduce, b64 P writes.
__global__ __launch_bounds__(256, 2)
void attn_fwd(const unsigned short* __restrict__ Q,
              const unsigned short* __restrict__ K,
              const unsigned short* __restrict__ Vt,
              const int* __restrict__ mask,
              unsigned short* __restrict__ Oa) {
  __shared__ __align__(16) unsigned short Ks[2][64 * 64];
  __shared__ __align__(16) unsigned short Vs[2][64 * 64];
  __shared__ __align__(16) unsigned short Ps[4][16][80];

  const int bid0 = blockIdx.x;
  const int wg = (bid0 & 7) * 256 + (bid0 >> 3);   // XCD swizzle (2048%8==0)
  const int qt = wg & 31;
  const int h = (wg >> 5) & 15;
  const int b = wg >> 9;
  const int tid = threadIdx.x;
  const int lane = tid & 63;
  const int wave = tid >> 6;
  const int fr = lane & 15;
  const int fg = lane >> 4;
  const int frow = fg * 4;

  const unsigned short* Qb = Q + (size_t)(b * 16 + h) * (2048 * 64);
  const unsigned short* Kb = K + (size_t)(b * 16 + h) * (2048 * 64);
  const unsigned short* Vb = Vt + (size_t)(b * 16 + h) * (64 * 2048);
  const int* Mb = mask + (size_t)b * (2048 * 2048);

  const int q0 = qt * 64 + wave * 16;

  bf16x8 qf0 = *(const bf16x8*)&Qb[(q0 + fr) * 64 + fg * 8];
  bf16x8 qf1 = *(const bf16x8*)&Qb[(q0 + fr) * 64 + 32 + fg * 8];

  f4 po[4];
#pragma unroll
  for (int nd = 0; nd < 4; ++nd) po[nd] = (f4){0.f, 0.f, 0.f, 0.f};
  float mr = -1e30f, lr = 0.f;

  const int c0 = wave * 2, c1 = wave * 2 + 1;
  const int krow0 = lane >> 3;
  const int kslot = (lane & 7) ^ (krow0 & 7);
  const unsigned short* kg0 = Kb + (size_t)(c0 * 8 + krow0) * 64 + kslot * 8;
  const unsigned short* kg1 = Kb + (size_t)(c1 * 8 + krow0) * 64 + kslot * 8;
  const unsigned short* vg0 = Vb + (size_t)(c0 * 8 + krow0) * 2048 + kslot * 8;
  const unsigned short* vg1 = Vb + (size_t)(c1 * 8 + krow0) * 2048 + kslot * 8;

  const int* mrow = Mb + (size_t)(q0 + fr) * 2048 + frow;

  // prologue: stage tile 0 -> buffer 0
  gload16(kg0, &Ks[0][c0 * 512]);
  gload16(kg1, &Ks[0][c1 * 512]);
  gload16(vg0, &Vs[0][c0 * 512]);
  gload16(vg1, &Vs[0][c1 * 512]);
  asm volatile("s_waitcnt vmcnt(0)" ::: "memory");
  __builtin_amdgcn_s_barrier();

  for (int kt = 0; kt < 32; ++kt) {
    const int cur = kt & 1;

    // mask loads FIRST (vector int4); issued before stage so their use
    // waits vmcnt(4), leaving next-tile stage loads in flight
    i32x4 mk[4];
#pragma unroll
    for (int nf = 0; nf < 4; ++nf)
      mk[nf] = *(const i32x4*)(mrow + kt * 64 + nf * 16);

    if (kt < 31) {
      const int nxt = cur ^ 1;
      gload16(kg0 + (size_t)(kt + 1) * 4096, &Ks[nxt][c0 * 512]);
      gload16(kg1 + (size_t)(kt + 1) * 4096, &Ks[nxt][c1 * 512]);
      gload16(vg0 + (kt + 1) * 64, &Vs[nxt][c0 * 512]);
      gload16(vg1 + (kt + 1) * 64, &Vs[nxt][c1 * 512]);
    }

    // S^T = K x Q^T : sf[nf][i] = S[q0+fr][kt*64 + nf*16 + fg*4 + i]
    f4 sf[4];
    __builtin_amdgcn_s_setprio(1);
#pragma unroll
    for (int nf = 0; nf < 4; ++nf) {
      int krow = nf * 16 + fr;
      int sw = krow & 7;
      bf16x8 kf0 = *(const bf16x8*)&Ks[cur][krow * 64 + ((fg ^ sw) * 8)];
      bf16x8 kf1 = *(const bf16x8*)&Ks[cur][krow * 64 + (((4 + fg) ^ sw) * 8)];
      f4 a = (f4){0.f, 0.f, 0.f, 0.f};
      a = mfma16(kf0, qf0, a);
      a = mfma16(kf1, qf1, a);
      sf[nf] = a;
    }
    __builtin_amdgcn_s_setprio(0);

    // scale+mask in exp2 space: cs = log2(e)/sqrt(C)
    const float cs = 0.045084439f;
#pragma unroll
    for (int nf = 0; nf < 4; ++nf)
#pragma unroll
      for (int i = 0; i < 4; ++i) {
        float sv = sf[nf][i] * cs;
        sf[nf][i] = (mk[nf][i] != 0) ? sv : -1e5f;
      }

    // row reduce: lane-local over 16 + 2 shuffles (row q=fr replicated x4 fg)
    float tm = sf[0][0];
#pragma unroll
    for (int nf = 0; nf < 4; ++nf)
#pragma unroll
      for (int i = 0; i < 4; ++i) tm = fmaxf(tm, sf[nf][i]);
    tm = fmaxf(tm, __shfl_xor(tm, 16));
    tm = fmaxf(tm, __shfl_xor(tm, 32));

    float mn = fmaxf(mr, tm);
    float corr = exp2f(mr - mn);
    mr = mn;

    float ls = 0.f;
#pragma unroll
    for (int nf = 0; nf < 4; ++nf)
#pragma unroll
      for (int i = 0; i < 4; ++i) {
        float p = exp2f(sf[nf][i] - mr);
        sf[nf][i] = p;
        ls += p;
      }
    ls += __shfl_xor(ls, 16);
    ls += __shfl_xor(ls, 32);
    lr = lr * corr + ls;

    // broadcast corr to po's row mapping (po rows are q=frow+i)
    float cb[4];
#pragma unroll
    for (int i = 0; i < 4; ++i) cb[i] = __shfl(corr, frow + i);
#pragma unroll
    for (int nd = 0; nd < 4; ++nd)
#pragma unroll
      for (int i = 0; i < 4; ++i) po[nd][i] *= cb[i];

    // P -> LDS: k-contiguous b64 writes (uniform bank spread at pad=80)
#pragma unroll
    for (int nf = 0; nf < 4; ++nf) {
      bf16x4 pk = { (__bf16)sf[nf][0], (__bf16)sf[nf][1],
                    (__bf16)sf[nf][2], (__bf16)sf[nf][3] };
      *(bf16x4*)&Ps[wave][fr][nf * 16 + frow] = pk;
    }
    bf16x8 pf0 = *(const bf16x8*)&Ps[wave][fr][fg * 8];
    bf16x8 pf1 = *(const bf16x8*)&Ps[wave][fr][32 + fg * 8];

    __builtin_amdgcn_s_setprio(1);
#pragma unroll
    for (int nd = 0; nd < 4; ++nd) {
      int vrow = nd * 16 + fr;
      int sw = vrow & 7;
      bf16x8 vf0 = *(const bf16x8*)&Vs[cur][vrow * 64 + ((fg ^ sw) * 8)];
      bf16x8 vf1 = *(const bf16x8*)&Vs[cur][vrow * 64 + (((4 + fg) ^ sw) * 8)];
      po[nd] = mfma16(pf0, vf0, po[nd]);
      po[nd] = mfma16(pf1, vf1, po[nd]);
    }
    __builtin_amdgcn_s_setprio(0);

    asm volatile("s_waitcnt vmcnt(0)" ::: "memory");
    __builtin_amdgcn_s_barrier();
  }

  // epilogue: out[b][t][h*64+d] bf16; l broadcast to po's row mapping
  float lv[4];
#pragma unroll
  for (int i = 0; i < 4; ++i) lv[i] = __shfl(lr, frow + i);
#pragma unroll
  for (int nd = 0; nd < 4; ++nd) {
    int col = h * 64 + nd * 16 + fr;
#pragma unroll
    for (int i = 0; i < 4; ++i) {
      int r = b * 2048 + q0 + frow + i;
      float o = po[nd][i] / lv[i];
      Oa[(size_t)r * 1024 + col] = f2bf(o);
    }
  }
}

// ---------------------------------------------------------------------------
extern "C" void kernel_launch(void* const* d_in, const int* in_sizes, int n_in,
                              void* d_out, int out_size, void* d_ws, size_t ws_size,
                              hipStream_t stream) {
  const float* x = (const float*)d_in[0];
  const int* mask = (const int*)d_in[1];
  const float* Wq = (const float*)d_in[2];
  const float* Wk = (const float*)d_in[3];
  const float* Wv = (const float*)d_in[4];
  const float* Wo = (const float*)d_in[5];
  float* out = (float*)d_out;
  char* ws = (char*)d_ws;

  float* cosT = (float*)(ws + 0x0);
  float* sinT = (float*)(ws + 0x80000);
  float* scT  = (float*)(ws + 0x100000);
  float* iscT = (float*)(ws + 0x180000);
  unsigned short* xb  = (unsigned short*)(ws + 0x200000);   // 16MB
  unsigned short* wqb = (unsigned short*)(ws + 0x1200000);  // 2MB each
  unsigned short* wkb = (unsigned short*)(ws + 0x1400000);
  unsigned short* wvb = (unsigned short*)(ws + 0x1600000);
  unsigned short* wob = (unsigned short*)(ws + 0x1800000);
  unsigned short* Qb  = (unsigned short*)(ws + 0x1A00000);  // 16MB each
  unsigned short* Kb  = (unsigned short*)(ws + 0x2A00000);
  unsigned short* Vtb = (unsigned short*)(ws + 0x3A00000);
  unsigned short* Aob = (unsigned short*)(ws + 0x4A00000);  // ends 0x5A00000

  prep_tables<<<(T_ * (D_ / 2) + 255) / 256, 256, 0, stream>>>(cosT, sinT, scT, iscT);
  cvt_bf16<<<(M_ * C_ / 4 + 255) / 256, 256, 0, stream>>>(x, xb, M_ * C_ / 4);
  cvt_bf16<<<(C_ * C_ / 4 + 255) / 256, 256, 0, stream>>>(Wq, wqb, C_ * C_ / 4);
  cvt_bf16<<<(C_ * C_ / 4 + 255) / 256, 256, 0, stream>>>(Wk, wkb, C_ * C_ / 4);
  cvt_bf16<<<(C_ * C_ / 4 + 255) / 256, 256, 0, stream>>>(Wv, wvb, C_ * C_ / 4);
  cvt_bf16<<<(C_ * C_ / 4 + 255) / 256, 256, 0, stream>>>(Wo, wob, C_ * C_ / 4);

  dim3 gq(C_ / 128, M_ / 128, 3);   // (8, 64, 3)
  gemm_qkv<<<gq, 256, 0, stream>>>(xb, wqb, wkb, wvb, Qb, Kb, Vtb,
                                   cosT, sinT, scT, iscT);

  attn_fwd<<<B_ * H_ * (T_ / 64), 256, 0, stream>>>(Qb, Kb, Vtb, mask, Aob);

  dim3 go(C_ / 128, M_ / 128);      // (8, 64)
  gemm_out<<<go, 256, 0, stream>>>(Aob, wob, out);
}

// Round 5
// 410.816 us; speedup vs baseline: 1.1810x; 1.1459x over previous
//
#include <hip/hip_runtime.h>
#include <stdint.h>

// Problem constants
#define B_ 4
#define T_ 2048
#define C_ 1024
#define H_ 16
#define D_ 64
#define M_ (B_*T_)   // 8192 rows in the projection GEMMs

typedef float f4 __attribute__((ext_vector_type(4)));
typedef float f32x4 __attribute__((ext_vector_type(4)));
typedef __bf16 bf16x8 __attribute__((ext_vector_type(8)));
typedef __bf16 bf16x4 __attribute__((ext_vector_type(4)));
typedef unsigned short u16x4 __attribute__((ext_vector_type(4)));

__device__ __forceinline__ unsigned short f2bf(float f) {
  unsigned u = __builtin_bit_cast(unsigned, f);
  u += 0x7fffu + ((u >> 16) & 1u);   // RNE
  return (unsigned short)(u >> 16);
}

__device__ __forceinline__ f4 mfma16(bf16x8 a, bf16x8 b, f4 c) {
  return __builtin_amdgcn_mfma_f32_16x16x32_bf16(a, b, c, 0, 0, 0);
}

__device__ __forceinline__ void gload16(const void* g, void* l) {
  __builtin_amdgcn_global_load_lds(
      (const __attribute__((address_space(1))) unsigned int*)g,
      (__attribute__((address_space(3))) unsigned int*)l, 16, 0, 0);
}

// ---------------- RoPE tables: cos/sin/scale/iscale, each [T][D] f32 -------
__global__ void prep_tables(float* __restrict__ cosT, float* __restrict__ sinT,
                            float* __restrict__ scT, float* __restrict__ iscT) {
  int idx = blockIdx.x * blockDim.x + threadIdx.x;   // T * D/2 = 65536
  if (idx >= T_ * (D_ / 2)) return;
  int t = idx >> 5;          // D/2 = 32
  int i = idx & 31;          // pair index
  float d2 = 2.0f * (float)i;
  float inv_freq = powf(10000.0f, -(d2 / 64.0f));
  float fr = (float)t * inv_freq;
  float c = cosf(fr), s = sinf(fr);
  float base = (d2 + 0.4f * 64.0f) / (1.4f * 64.0f);
  float pw = ((float)t - 1024.0f) / 512.0f;
  float sc = powf(base, pw);
  int o = t * 64 + i * 2;
  cosT[o] = c; cosT[o + 1] = c;
  sinT[o] = s; sinT[o + 1] = s;
  scT[o] = sc; scT[o + 1] = sc;
  iscT[o] = 1.0f / sc; iscT[o + 1] = 1.0f / sc;
}

// ---------------- f32 -> bf16 conversion ----------------------------------
__global__ void cvt_bf16(const float* __restrict__ src,
                         unsigned short* __restrict__ dst, int n4) {
  int i = blockIdx.x * blockDim.x + threadIdx.x;
  if (i >= n4) return;
  f32x4 v = *(const f32x4*)(src + (size_t)i * 4);
  u16x4 o;
  o[0] = f2bf(v[0]); o[1] = f2bf(v[1]); o[2] = f2bf(v[2]); o[3] = f2bf(v[3]);
  *(u16x4*)(dst + (size_t)i * 4) = o;
}

// ---------------- mask bit-pack: int32[4][2048][2048] -> u64[4][2048][32] ---
// one wave packs 4 consecutive 64-int groups via __ballot
__global__ void pack_mask(const int* __restrict__ mask,
                          unsigned long long* __restrict__ bits) {
  int wv = (blockIdx.x * blockDim.x + threadIdx.x) >> 6;   // global wave id
  int lane = threadIdx.x & 63;
  size_t base = (size_t)wv * 4;
#pragma unroll
  for (int j = 0; j < 4; ++j) {
    int v = mask[(base + j) * 64 + lane];
    unsigned long long w = __ballot(v != 0);
    if (lane == 0) bits[base + j] = w;
  }
}

// ---------------- fused QKV GEMM: out[r][n] = sum_k A[r][k] * W[n][k] ------
// blockIdx.z: 0=Q (rope*scale*log2e/32), 1=K (rope/scale), 2=V (transposed)
__global__ __launch_bounds__(256, 2)
void gemm_qkv(const unsigned short* __restrict__ A,
              const unsigned short* __restrict__ Wq,
              const unsigned short* __restrict__ Wk,
              const unsigned short* __restrict__ Wv,
              unsigned short* __restrict__ Qo,
              unsigned short* __restrict__ Ko,
              unsigned short* __restrict__ Vo,
              const float* __restrict__ cosT,
              const float* __restrict__ sinT,
              const float* __restrict__ scT,
              const float* __restrict__ iscT) {
  __shared__ __align__(16) unsigned short As[2][128 * 32];
  __shared__ __align__(16) unsigned short Bs[2][128 * 32];

  const int z = blockIdx.z;
  const unsigned short* W = (z == 0) ? Wq : (z == 1) ? Wk : Wv;

  const int tid = threadIdx.x;
  const int lane = tid & 63;
  const int wave = tid >> 6;
  const int m0 = blockIdx.y * 128;
  const int n0 = blockIdx.x * 128;
  const int wm = (wave >> 1) * 64;
  const int wn = (wave & 1) * 64;
  const int fr = lane & 15;
  const int fg = lane >> 4;

  f4 acc[4][4];
#pragma unroll
  for (int mi = 0; mi < 4; ++mi)
#pragma unroll
    for (int ni = 0; ni < 4; ++ni) acc[mi][ni] = (f4){0.f, 0.f, 0.f, 0.f};

  const int c0 = wave * 2, c1 = wave * 2 + 1;
  const int srow = lane >> 2;
  const int sslot = (lane & 3) ^ (srow & 3);
  const unsigned short* a0 = A + (size_t)(m0 + c0 * 16 + srow) * 1024 + sslot * 8;
  const unsigned short* a1 = A + (size_t)(m0 + c1 * 16 + srow) * 1024 + sslot * 8;
  const unsigned short* b0 = W + (size_t)(n0 + c0 * 16 + srow) * 1024 + sslot * 8;
  const unsigned short* b1 = W + (size_t)(n0 + c1 * 16 + srow) * 1024 + sslot * 8;

  // prologue: stage k0=0 into buffer 0
  gload16(a0, &As[0][c0 * 512]);
  gload16(a1, &As[0][c1 * 512]);
  gload16(b0, &Bs[0][c0 * 512]);
  gload16(b1, &Bs[0][c1 * 512]);
  asm volatile("s_waitcnt vmcnt(0)" ::: "memory");
  __builtin_amdgcn_s_barrier();

  for (int k0 = 0; k0 < 1024; k0 += 32) {
    const int cur = (k0 >> 5) & 1;
    if (k0 + 32 < 1024) {
      const int nxt = cur ^ 1;
      gload16(a0 + k0 + 32, &As[nxt][c0 * 512]);
      gload16(a1 + k0 + 32, &As[nxt][c1 * 512]);
      gload16(b0 + k0 + 32, &Bs[nxt][c0 * 512]);
      gload16(b1 + k0 + 32, &Bs[nxt][c1 * 512]);
    }
    bf16x8 af[4], bfr[4];
#pragma unroll
    for (int mi = 0; mi < 4; ++mi) {
      int row = wm + mi * 16 + fr;
      af[mi] = *(const bf16x8*)&As[cur][row * 32 + ((fg ^ (fr & 3)) * 8)];
    }
#pragma unroll
    for (int ni = 0; ni < 4; ++ni) {
      int row = wn + ni * 16 + fr;
      bfr[ni] = *(const bf16x8*)&Bs[cur][row * 32 + ((fg ^ (fr & 3)) * 8)];
    }
#pragma unroll
    for (int mi = 0; mi < 4; ++mi)
#pragma unroll
      for (int ni = 0; ni < 4; ++ni)
        acc[mi][ni] = mfma16(af[mi], bfr[ni], acc[mi][ni]);
    asm volatile("s_waitcnt vmcnt(0)" ::: "memory");
    __builtin_amdgcn_s_barrier();
  }

  const int frow = fg * 4;

  if (z == 2) {
    // V: store transposed [B][H][D][T]
#pragma unroll
    for (int mi = 0; mi < 4; ++mi) {
      int r0 = m0 + wm + mi * 16 + frow;
      int b = r0 >> 11, t0v = r0 & 2047;
#pragma unroll
      for (int ni = 0; ni < 4; ++ni) {
        int n = n0 + wn + ni * 16 + fr;
        size_t base = ((size_t)(b * 16 + (n >> 6)) * 64 + (n & 63)) * 2048 + t0v;
        u16x4 pk;
        pk[0] = f2bf(acc[mi][ni][0]);
        pk[1] = f2bf(acc[mi][ni][1]);
        pk[2] = f2bf(acc[mi][ni][2]);
        pk[3] = f2bf(acc[mi][ni][3]);
        *(u16x4*)&Vo[base] = pk;
      }
    }
  } else {
    unsigned short* O = (z == 0) ? Qo : Ko;
    const float* sT = (z == 0) ? scT : iscT;
    // Q additionally absorbs log2(e)/sqrt(C) so attn needs no scale mul
    const float post = (z == 0) ? 0.04508443895f : 1.0f;
#pragma unroll
    for (int mi = 0; mi < 4; ++mi)
#pragma unroll
      for (int ni = 0; ni < 4; ++ni) {
        int n = n0 + wn + ni * 16 + fr;
        int d = n & 63, hh = n >> 6;
#pragma unroll
        for (int i = 0; i < 4; ++i) {
          int r = m0 + wm + mi * 16 + frow + i;
          int t = r & 2047, b = r >> 11;
          float v = acc[mi][ni][i];
          float p = __shfl_xor(v, 1);
          int o = t * 64 + d;
          float cv = cosT[o], sv = sinT[o], scv = sT[o];
          float rot = (d & 1) ? p : -p;
          float res = (v * cv + rot * sv) * scv * post;
          O[((size_t)(b * 16 + hh) * 2048 + t) * 64 + d] = f2bf(res);
        }
      }
  }
}

// ---------------- output GEMM (f32 out) ------------------------------------
__global__ __launch_bounds__(256, 2)
void gemm_out(const unsigned short* __restrict__ A,
              const unsigned short* __restrict__ W,
              float* __restrict__ O) {
  __shared__ __align__(16) unsigned short As[2][128 * 32];
  __shared__ __align__(16) unsigned short Bs[2][128 * 32];

  const int tid = threadIdx.x;
  const int lane = tid & 63;
  const int wave = tid >> 6;
  const int m0 = blockIdx.y * 128;
  const int n0 = blockIdx.x * 128;
  const int wm = (wave >> 1) * 64;
  const int wn = (wave & 1) * 64;
  const int fr = lane & 15;
  const int fg = lane >> 4;

  f4 acc[4][4];
#pragma unroll
  for (int mi = 0; mi < 4; ++mi)
#pragma unroll
    for (int ni = 0; ni < 4; ++ni) acc[mi][ni] = (f4){0.f, 0.f, 0.f, 0.f};

  const int c0 = wave * 2, c1 = wave * 2 + 1;
  const int srow = lane >> 2;
  const int sslot = (lane & 3) ^ (srow & 3);
  const unsigned short* a0 = A + (size_t)(m0 + c0 * 16 + srow) * 1024 + sslot * 8;
  const unsigned short* a1 = A + (size_t)(m0 + c1 * 16 + srow) * 1024 + sslot * 8;
  const unsigned short* b0 = W + (size_t)(n0 + c0 * 16 + srow) * 1024 + sslot * 8;
  const unsigned short* b1 = W + (size_t)(n0 + c1 * 16 + srow) * 1024 + sslot * 8;

  gload16(a0, &As[0][c0 * 512]);
  gload16(a1, &As[0][c1 * 512]);
  gload16(b0, &Bs[0][c0 * 512]);
  gload16(b1, &Bs[0][c1 * 512]);
  asm volatile("s_waitcnt vmcnt(0)" ::: "memory");
  __builtin_amdgcn_s_barrier();

  for (int k0 = 0; k0 < 1024; k0 += 32) {
    const int cur = (k0 >> 5) & 1;
    if (k0 + 32 < 1024) {
      const int nxt = cur ^ 1;
      gload16(a0 + k0 + 32, &As[nxt][c0 * 512]);
      gload16(a1 + k0 + 32, &As[nxt][c1 * 512]);
      gload16(b0 + k0 + 32, &Bs[nxt][c0 * 512]);
      gload16(b1 + k0 + 32, &Bs[nxt][c1 * 512]);
    }
    bf16x8 af[4], bfr[4];
#pragma unroll
    for (int mi = 0; mi < 4; ++mi) {
      int row = wm + mi * 16 + fr;
      af[mi] = *(const bf16x8*)&As[cur][row * 32 + ((fg ^ (fr & 3)) * 8)];
    }
#pragma unroll
    for (int ni = 0; ni < 4; ++ni) {
      int row = wn + ni * 16 + fr;
      bfr[ni] = *(const bf16x8*)&Bs[cur][row * 32 + ((fg ^ (fr & 3)) * 8)];
    }
#pragma unroll
    for (int mi = 0; mi < 4; ++mi)
#pragma unroll
      for (int ni = 0; ni < 4; ++ni)
        acc[mi][ni] = mfma16(af[mi], bfr[ni], acc[mi][ni]);
    asm volatile("s_waitcnt vmcnt(0)" ::: "memory");
    __builtin_amdgcn_s_barrier();
  }

  const int frow = fg * 4;
#pragma unroll
  for (int mi = 0; mi < 4; ++mi)
#pragma unroll
    for (int ni = 0; ni < 4; ++ni) {
      int n = n0 + wn + ni * 16 + fr;
#pragma unroll
      for (int i = 0; i < 4; ++i) {
        int r = m0 + wm + mi * 16 + frow + i;
        O[(size_t)r * 1024 + n] = acc[mi][ni][i];
      }
    }
}

// ---------------- flash attention v3 ---------------------------------------
// 8 waves (512 thr), QBLK=128 (16 q-rows/wave), KVBLK=64, grid 1024 blocks.
// Swapped QK^T: lane holds S[q=fr][k=16nf+4fg+i], log2e/sqrtC pre-folded in Q.
// NO online max (inputs bounded: exp2 args |s|<~80, f32-safe; softmax is
// shift-invariant). l accumulates per-lane; single cross-lane reduce at end.
// Mask as bit-words: u64 per (q-row, 64-k tile), L2-resident (2MB).
__global__ __launch_bounds__(512, 6)
void attn_fwd(const unsigned short* __restrict__ Q,
              const unsigned short* __restrict__ K,
              const unsigned short* __restrict__ Vt,
              const unsigned long long* __restrict__ Mbits,
              unsigned short* __restrict__ Oa) {
  __shared__ __align__(16) unsigned short Ks[2][64 * 64];
  __shared__ __align__(16) unsigned short Vs[2][64 * 64];
  __shared__ __align__(16) unsigned short Ps[8][16][72];

  const int bid0 = blockIdx.x;
  const int wg = (bid0 & 7) * 128 + (bid0 >> 3);   // XCD swizzle (1024%8==0)
  const int qt = wg & 15;          // T/128 = 16 q-tiles
  const int h = (wg >> 4) & 15;
  const int b = wg >> 8;
  const int tid = threadIdx.x;
  const int lane = tid & 63;
  const int wave = tid >> 6;       // 0..7
  const int fr = lane & 15;
  const int fg = lane >> 4;
  const int frow = fg * 4;

  const unsigned short* Qb = Q + (size_t)(b * 16 + h) * (2048 * 64);
  const unsigned short* Kb = K + (size_t)(b * 16 + h) * (2048 * 64);
  const unsigned short* Vb = Vt + (size_t)(b * 16 + h) * (64 * 2048);

  const int q0 = qt * 128 + wave * 16;

  bf16x8 qf0 = *(const bf16x8*)&Qb[(q0 + fr) * 64 + fg * 8];
  bf16x8 qf1 = *(const bf16x8*)&Qb[(q0 + fr) * 64 + 32 + fg * 8];

  f4 po[4];
#pragma unroll
  for (int nd = 0; nd < 4; ++nd) po[nd] = (f4){0.f, 0.f, 0.f, 0.f};
  float lr = 0.f;   // per-lane partial denominator (own 16 k-cols per tile)

  // staging: each wave stages one 8-row chunk of K and of V (1KB each)
  const int krow0 = lane >> 3;
  const int kslot = (lane & 7) ^ (krow0 & 7);
  const unsigned short* kg = Kb + (size_t)(wave * 8 + krow0) * 64 + kslot * 8;
  const unsigned short* vg = Vb + (size_t)(wave * 8 + krow0) * 2048 + kslot * 8;

  const unsigned long long* mrow = Mbits + (size_t)(b * 2048 + q0 + fr) * 32;

  // prologue: stage tile 0 -> buffer 0
  gload16(kg, &Ks[0][wave * 512]);
  gload16(vg, &Vs[0][wave * 512]);
  asm volatile("s_waitcnt vmcnt(0)" ::: "memory");
  __builtin_amdgcn_s_barrier();

  for (int kt = 0; kt < 32; ++kt) {
    const int cur = kt & 1;

    // mask bits for this lane's q-row, this 64-k tile (L2-resident)
    unsigned long long w = mrow[kt];

    if (kt < 31) {
      const int nxt = cur ^ 1;
      gload16(kg + (size_t)(kt + 1) * 4096, &Ks[nxt][wave * 512]);
      gload16(vg + (kt + 1) * 64, &Vs[nxt][wave * 512]);
    }

    // S^T = K x Q^T : sf[nf][i] = S[q0+fr][kt*64 + nf*16 + fg*4 + i]
    f4 sf[4];
    __builtin_amdgcn_s_setprio(1);
#pragma unroll
    for (int nf = 0; nf < 4; ++nf) {
      int krow = nf * 16 + fr;
      int sw = krow & 7;
      bf16x8 kf0 = *(const bf16x8*)&Ks[cur][krow * 64 + ((fg ^ sw) * 8)];
      bf16x8 kf1 = *(const bf16x8*)&Ks[cur][krow * 64 + (((4 + fg) ^ sw) * 8)];
      f4 a = (f4){0.f, 0.f, 0.f, 0.f};
      a = mfma16(kf0, qf0, a);
      a = mfma16(kf1, qf1, a);
      sf[nf] = a;
    }
    __builtin_amdgcn_s_setprio(0);

    // p = mask ? exp2(s) : 0  (scale pre-folded in Q; no max, no rescale)
    unsigned lo = (unsigned)w >> (fg * 4);
    unsigned hi = (unsigned)(w >> 32) >> (fg * 4);
#pragma unroll
    for (int nf = 0; nf < 4; ++nf) {
      unsigned wsel = (nf & 2) ? hi : lo;
#pragma unroll
      for (int i = 0; i < 4; ++i) {
        float p = exp2f(sf[nf][i]);
        if (!((wsel >> (((nf & 1) << 4) + i)) & 1)) p = 0.f;
        sf[nf][i] = p;
        lr += p;
      }
    }

    // P -> LDS (b64 writes), re-read as A-fragments (wave-local)
#pragma unroll
    for (int nf = 0; nf < 4; ++nf) {
      bf16x4 pk = { (__bf16)sf[nf][0], (__bf16)sf[nf][1],
                    (__bf16)sf[nf][2], (__bf16)sf[nf][3] };
      *(bf16x4*)&Ps[wave][fr][nf * 16 + frow] = pk;
    }
    bf16x8 pf0 = *(const bf16x8*)&Ps[wave][fr][fg * 8];
    bf16x8 pf1 = *(const bf16x8*)&Ps[wave][fr][32 + fg * 8];

    __builtin_amdgcn_s_setprio(1);
#pragma unroll
    for (int nd = 0; nd < 4; ++nd) {
      int vrow = nd * 16 + fr;
      int sw = vrow & 7;
      bf16x8 vf0 = *(const bf16x8*)&Vs[cur][vrow * 64 + ((fg ^ sw) * 8)];
      bf16x8 vf1 = *(const bf16x8*)&Vs[cur][vrow * 64 + (((4 + fg) ^ sw) * 8)];
      po[nd] = mfma16(pf0, vf0, po[nd]);
      po[nd] = mfma16(pf1, vf1, po[nd]);
    }
    __builtin_amdgcn_s_setprio(0);

    asm volatile("s_waitcnt vmcnt(0)" ::: "memory");
    __builtin_amdgcn_s_barrier();
  }

  // epilogue: reduce l across the 4 fg replicas, divide, store bf16
  lr += __shfl_xor(lr, 16);
  lr += __shfl_xor(lr, 32);
  float lv[4];
#pragma unroll
  for (int i = 0; i < 4; ++i) lv[i] = __shfl(lr, frow + i);
#pragma unroll
  for (int nd = 0; nd < 4; ++nd) {
    int col = h * 64 + nd * 16 + fr;
#pragma unroll
    for (int i = 0; i < 4; ++i) {
      int r = b * 2048 + q0 + frow + i;
      float o = po[nd][i] / lv[i];
      Oa[(size_t)r * 1024 + col] = f2bf(o);
    }
  }
}

// ---------------------------------------------------------------------------
extern "C" void kernel_launch(void* const* d_in, const int* in_sizes, int n_in,
                              void* d_out, int out_size, void* d_ws, size_t ws_size,
                              hipStream_t stream) {
  const float* x = (const float*)d_in[0];
  const int* mask = (const int*)d_in[1];
  const float* Wq = (const float*)d_in[2];
  const float* Wk = (const float*)d_in[3];
  const float* Wv = (const float*)d_in[4];
  const float* Wo = (const float*)d_in[5];
  float* out = (float*)d_out;
  char* ws = (char*)d_ws;

  float* cosT = (float*)(ws + 0x0);
  float* sinT = (float*)(ws + 0x80000);
  float* scT  = (float*)(ws + 0x100000);
  float* iscT = (float*)(ws + 0x180000);
  // mask bits (2MB) ALIAS the tables region: written after gemm_qkv is done
  unsigned long long* mbits = (unsigned long long*)(ws + 0x0);
  unsigned short* xb  = (unsigned short*)(ws + 0x200000);   // 16MB
  unsigned short* wqb = (unsigned short*)(ws + 0x1200000);  // 2MB each
  unsigned short* wkb = (unsigned short*)(ws + 0x1400000);
  unsigned short* wvb = (unsigned short*)(ws + 0x1600000);
  unsigned short* wob = (unsigned short*)(ws + 0x1800000);
  unsigned short* Qb  = (unsigned short*)(ws + 0x1A00000);  // 16MB each
  unsigned short* Kb  = (unsigned short*)(ws + 0x2A00000);
  unsigned short* Vtb = (unsigned short*)(ws + 0x3A00000);
  unsigned short* Aob = (unsigned short*)(ws + 0x4A00000);  // ends 0x5A00000

  prep_tables<<<(T_ * (D_ / 2) + 255) / 256, 256, 0, stream>>>(cosT, sinT, scT, iscT);
  cvt_bf16<<<(M_ * C_ / 4 + 255) / 256, 256, 0, stream>>>(x, xb, M_ * C_ / 4);
  cvt_bf16<<<(C_ * C_ / 4 + 255) / 256, 256, 0, stream>>>(Wq, wqb, C_ * C_ / 4);
  cvt_bf16<<<(C_ * C_ / 4 + 255) / 256, 256, 0, stream>>>(Wk, wkb, C_ * C_ / 4);
  cvt_bf16<<<(C_ * C_ / 4 + 255) / 256, 256, 0, stream>>>(Wv, wvb, C_ * C_ / 4);
  cvt_bf16<<<(C_ * C_ / 4 + 255) / 256, 256, 0, stream>>>(Wo, wob, C_ * C_ / 4);

  dim3 gq(C_ / 128, M_ / 128, 3);   // (8, 64, 3)
  gemm_qkv<<<gq, 256, 0, stream>>>(xb, wqb, wkb, wvb, Qb, Kb, Vtb,
                                   cosT, sinT, scT, iscT);

  // pack mask AFTER gemm_qkv (mbits aliases the then-dead RoPE tables)
  pack_mask<<<16384, 256, 0, stream>>>(mask, mbits);

  attn_fwd<<<B_ * H_ * (T_ / 128), 512, 0, stream>>>(Qb, Kb, Vtb, mbits, Aob);

  dim3 go(C_ / 128, M_ / 128);      // (8, 64)
  gemm_out<<<go, 256, 0, stream>>>(Aob, wob, out);
}

// Round 6
// 364.675 us; speedup vs baseline: 1.3304x; 1.1265x over previous
//
#include <hip/hip_runtime.h>
#include <stdint.h>

// Problem constants
#define B_ 4
#define T_ 2048
#define C_ 1024
#define H_ 16
#define D_ 64
#define M_ (B_*T_)   // 8192 rows in the projection GEMMs

typedef float f4 __attribute__((ext_vector_type(4)));
typedef float f32x4 __attribute__((ext_vector_type(4)));
typedef __bf16 bf16x8 __attribute__((ext_vector_type(8)));
typedef __bf16 bf16x4 __attribute__((ext_vector_type(4)));
typedef unsigned short u16x4 __attribute__((ext_vector_type(4)));

__device__ __forceinline__ unsigned short f2bf(float f) {
  unsigned u = __builtin_bit_cast(unsigned, f);
  u += 0x7fffu + ((u >> 16) & 1u);   // RNE
  return (unsigned short)(u >> 16);
}

__device__ __forceinline__ f4 mfma16(bf16x8 a, bf16x8 b, f4 c) {
  return __builtin_amdgcn_mfma_f32_16x16x32_bf16(a, b, c, 0, 0, 0);
}

__device__ __forceinline__ void gload16(const void* g, void* l) {
  __builtin_amdgcn_global_load_lds(
      (const __attribute__((address_space(1))) unsigned int*)g,
      (__attribute__((address_space(3))) unsigned int*)l, 16, 0, 0);
}

// ---------------- RoPE tables: cos/sin/scale/iscale, each [T][D] f32 -------
__global__ void prep_tables(float* __restrict__ cosT, float* __restrict__ sinT,
                            float* __restrict__ scT, float* __restrict__ iscT) {
  int idx = blockIdx.x * blockDim.x + threadIdx.x;   // T * D/2 = 65536
  if (idx >= T_ * (D_ / 2)) return;
  int t = idx >> 5;          // D/2 = 32
  int i = idx & 31;          // pair index
  float d2 = 2.0f * (float)i;
  float inv_freq = powf(10000.0f, -(d2 / 64.0f));
  float fr = (float)t * inv_freq;
  float c = cosf(fr), s = sinf(fr);
  float base = (d2 + 0.4f * 64.0f) / (1.4f * 64.0f);
  float pw = ((float)t - 1024.0f) / 512.0f;
  float sc = powf(base, pw);
  int o = t * 64 + i * 2;
  cosT[o] = c; cosT[o + 1] = c;
  sinT[o] = s; sinT[o + 1] = s;
  scT[o] = sc; scT[o + 1] = sc;
  iscT[o] = 1.0f / sc; iscT[o + 1] = 1.0f / sc;
}

// ---------------- fused f32 -> bf16 conversions (x + 4 weights, 1 launch) --
__global__ void cvt_all(const float* __restrict__ x,
                        const float* __restrict__ wq, const float* __restrict__ wk,
                        const float* __restrict__ wv, const float* __restrict__ wo,
                        unsigned short* __restrict__ xb,
                        unsigned short* __restrict__ wqb, unsigned short* __restrict__ wkb,
                        unsigned short* __restrict__ wvb, unsigned short* __restrict__ wob) {
  int bid = blockIdx.x;
  const float* src; unsigned short* dst; int i;
  if (bid < 8192) {                       // x: 8M elems / 4 = 2M threads
    src = x; dst = xb; i = bid * 256 + threadIdx.x;
  } else {                                // weights: 1M elems / 4 = 256K each
    int r = bid - 8192;
    int w = r >> 10;
    src = (w == 0) ? wq : (w == 1) ? wk : (w == 2) ? wv : wo;
    dst = (w == 0) ? wqb : (w == 1) ? wkb : (w == 2) ? wvb : wob;
    i = (r & 1023) * 256 + threadIdx.x;
  }
  f32x4 v = *(const f32x4*)(src + (size_t)i * 4);
  u16x4 o;
  o[0] = f2bf(v[0]); o[1] = f2bf(v[1]); o[2] = f2bf(v[2]); o[3] = f2bf(v[3]);
  *(u16x4*)(dst + (size_t)i * 4) = o;
}

// ---------------- mask bit-pack: int32[4][2048][2048] -> u64[4][2048][32] ---
__global__ void pack_mask(const int* __restrict__ mask,
                          unsigned long long* __restrict__ bits) {
  int wv = (blockIdx.x * blockDim.x + threadIdx.x) >> 6;   // global wave id
  int lane = threadIdx.x & 63;
  size_t base = (size_t)wv * 4;
#pragma unroll
  for (int j = 0; j < 4; ++j) {
    int v = mask[(base + j) * 64 + lane];
    unsigned long long w = __ballot(v != 0);
    if (lane == 0) bits[base + j] = w;
  }
}

// ---------------- fused QKV GEMM: out[r][n] = sum_k A[r][k] * W[n][k] ------
// XCD-grouped id remap: each XCD owns 8 contiguous M-panels for all N,z.
__global__ __launch_bounds__(256, 3)
void gemm_qkv(const unsigned short* __restrict__ A,
              const unsigned short* __restrict__ Wq,
              const unsigned short* __restrict__ Wk,
              const unsigned short* __restrict__ Wv,
              unsigned short* __restrict__ Qo,
              unsigned short* __restrict__ Ko,
              unsigned short* __restrict__ Vo,
              const float* __restrict__ cosT,
              const float* __restrict__ sinT,
              const float* __restrict__ scT,
              const float* __restrict__ iscT) {
  __shared__ __align__(16) unsigned short As[2][128 * 32];
  __shared__ __align__(16) unsigned short Bs[2][128 * 32];

  // linear hw id -> (x=N-tile, y=M-panel, z=matrix); XCD = id&7 keeps one
  // y-group resident per XCD L2 across all x,z.
  const int id = blockIdx.x + 8 * blockIdx.y + 512 * blockIdx.z;
  const int xcd = id & 7;
  const int rest = id >> 3;               // 0..191
  const int by = xcd * 8 + (rest & 7);    // 0..63
  const int bx = (rest >> 3) & 7;         // 0..7
  const int z = rest >> 6;                // 0..2

  const unsigned short* W = (z == 0) ? Wq : (z == 1) ? Wk : Wv;

  const int tid = threadIdx.x;
  const int lane = tid & 63;
  const int wave = tid >> 6;
  const int m0 = by * 128;
  const int n0 = bx * 128;
  const int wm = (wave >> 1) * 64;
  const int wn = (wave & 1) * 64;
  const int fr = lane & 15;
  const int fg = lane >> 4;

  f4 acc[4][4];
#pragma unroll
  for (int mi = 0; mi < 4; ++mi)
#pragma unroll
    for (int ni = 0; ni < 4; ++ni) acc[mi][ni] = (f4){0.f, 0.f, 0.f, 0.f};

  const int c0 = wave * 2, c1 = wave * 2 + 1;
  const int srow = lane >> 2;
  const int sslot = (lane & 3) ^ (srow & 3);
  const unsigned short* a0 = A + (size_t)(m0 + c0 * 16 + srow) * 1024 + sslot * 8;
  const unsigned short* a1 = A + (size_t)(m0 + c1 * 16 + srow) * 1024 + sslot * 8;
  const unsigned short* b0 = W + (size_t)(n0 + c0 * 16 + srow) * 1024 + sslot * 8;
  const unsigned short* b1 = W + (size_t)(n0 + c1 * 16 + srow) * 1024 + sslot * 8;

  gload16(a0, &As[0][c0 * 512]);
  gload16(a1, &As[0][c1 * 512]);
  gload16(b0, &Bs[0][c0 * 512]);
  gload16(b1, &Bs[0][c1 * 512]);
  asm volatile("s_waitcnt vmcnt(0)" ::: "memory");
  __builtin_amdgcn_s_barrier();

#pragma unroll 2
  for (int k0 = 0; k0 < 1024; k0 += 32) {
    const int cur = (k0 >> 5) & 1;
    if (k0 + 32 < 1024) {
      const int nxt = cur ^ 1;
      gload16(a0 + k0 + 32, &As[nxt][c0 * 512]);
      gload16(a1 + k0 + 32, &As[nxt][c1 * 512]);
      gload16(b0 + k0 + 32, &Bs[nxt][c0 * 512]);
      gload16(b1 + k0 + 32, &Bs[nxt][c1 * 512]);
    }
    bf16x8 af[4], bfr[4];
#pragma unroll
    for (int mi = 0; mi < 4; ++mi) {
      int row = wm + mi * 16 + fr;
      af[mi] = *(const bf16x8*)&As[cur][row * 32 + ((fg ^ (fr & 3)) * 8)];
    }
#pragma unroll
    for (int ni = 0; ni < 4; ++ni) {
      int row = wn + ni * 16 + fr;
      bfr[ni] = *(const bf16x8*)&Bs[cur][row * 32 + ((fg ^ (fr & 3)) * 8)];
    }
#pragma unroll
    for (int mi = 0; mi < 4; ++mi)
#pragma unroll
      for (int ni = 0; ni < 4; ++ni)
        acc[mi][ni] = mfma16(af[mi], bfr[ni], acc[mi][ni]);
    asm volatile("s_waitcnt vmcnt(0)" ::: "memory");
    __builtin_amdgcn_s_barrier();
  }

  const int frow = fg * 4;

  if (z == 2) {
    // V: store transposed [B][H][D][T]
#pragma unroll
    for (int mi = 0; mi < 4; ++mi) {
      int r0 = m0 + wm + mi * 16 + frow;
      int b = r0 >> 11, t0v = r0 & 2047;
#pragma unroll
      for (int ni = 0; ni < 4; ++ni) {
        int n = n0 + wn + ni * 16 + fr;
        size_t base = ((size_t)(b * 16 + (n >> 6)) * 64 + (n & 63)) * 2048 + t0v;
        u16x4 pk;
        pk[0] = f2bf(acc[mi][ni][0]);
        pk[1] = f2bf(acc[mi][ni][1]);
        pk[2] = f2bf(acc[mi][ni][2]);
        pk[3] = f2bf(acc[mi][ni][3]);
        *(u16x4*)&Vo[base] = pk;
      }
    }
  } else {
    unsigned short* O = (z == 0) ? Qo : Ko;
    const float* sT = (z == 0) ? scT : iscT;
    // Q absorbs log2(e)/sqrt(C) so attn needs no scale mul
    const float post = (z == 0) ? 0.04508443895f : 1.0f;
#pragma unroll
    for (int mi = 0; mi < 4; ++mi)
#pragma unroll
      for (int ni = 0; ni < 4; ++ni) {
        int n = n0 + wn + ni * 16 + fr;
        int d = n & 63, hh = n >> 6;
#pragma unroll
        for (int i = 0; i < 4; ++i) {
          int r = m0 + wm + mi * 16 + frow + i;
          int t = r & 2047, b = r >> 11;
          float v = acc[mi][ni][i];
          float p = __shfl_xor(v, 1);
          int o = t * 64 + d;
          float cv = cosT[o], sv = sinT[o], scv = sT[o];
          float rot = (d & 1) ? p : -p;
          float res = (v * cv + rot * sv) * scv * post;
          O[((size_t)(b * 16 + hh) * 2048 + t) * 64 + d] = f2bf(res);
        }
      }
  }
}

// ---------------- output GEMM (f32 out) ------------------------------------
__global__ __launch_bounds__(256, 3)
void gemm_out(const unsigned short* __restrict__ A,
              const unsigned short* __restrict__ W,
              float* __restrict__ O) {
  __shared__ __align__(16) unsigned short As[2][128 * 32];
  __shared__ __align__(16) unsigned short Bs[2][128 * 32];

  const int id = blockIdx.x + 8 * blockIdx.y;
  const int xcd = id & 7;
  const int rest = id >> 3;               // 0..63
  const int by = xcd * 8 + (rest & 7);
  const int bx = (rest >> 3) & 7;

  const int tid = threadIdx.x;
  const int lane = tid & 63;
  const int wave = tid >> 6;
  const int m0 = by * 128;
  const int n0 = bx * 128;
  const int wm = (wave >> 1) * 64;
  const int wn = (wave & 1) * 64;
  const int fr = lane & 15;
  const int fg = lane >> 4;

  f4 acc[4][4];
#pragma unroll
  for (int mi = 0; mi < 4; ++mi)
#pragma unroll
    for (int ni = 0; ni < 4; ++ni) acc[mi][ni] = (f4){0.f, 0.f, 0.f, 0.f};

  const int c0 = wave * 2, c1 = wave * 2 + 1;
  const int srow = lane >> 2;
  const int sslot = (lane & 3) ^ (srow & 3);
  const unsigned short* a0 = A + (size_t)(m0 + c0 * 16 + srow) * 1024 + sslot * 8;
  const unsigned short* a1 = A + (size_t)(m0 + c1 * 16 + srow) * 1024 + sslot * 8;
  const unsigned short* b0 = W + (size_t)(n0 + c0 * 16 + srow) * 1024 + sslot * 8;
  const unsigned short* b1 = W + (size_t)(n0 + c1 * 16 + srow) * 1024 + sslot * 8;

  gload16(a0, &As[0][c0 * 512]);
  gload16(a1, &As[0][c1 * 512]);
  gload16(b0, &Bs[0][c0 * 512]);
  gload16(b1, &Bs[0][c1 * 512]);
  asm volatile("s_waitcnt vmcnt(0)" ::: "memory");
  __builtin_amdgcn_s_barrier();

#pragma unroll 2
  for (int k0 = 0; k0 < 1024; k0 += 32) {
    const int cur = (k0 >> 5) & 1;
    if (k0 + 32 < 1024) {
      const int nxt = cur ^ 1;
      gload16(a0 + k0 + 32, &As[nxt][c0 * 512]);
      gload16(a1 + k0 + 32, &As[nxt][c1 * 512]);
      gload16(b0 + k0 + 32, &Bs[nxt][c0 * 512]);
      gload16(b1 + k0 + 32, &Bs[nxt][c1 * 512]);
    }
    bf16x8 af[4], bfr[4];
#pragma unroll
    for (int mi = 0; mi < 4; ++mi) {
      int row = wm + mi * 16 + fr;
      af[mi] = *(const bf16x8*)&As[cur][row * 32 + ((fg ^ (fr & 3)) * 8)];
    }
#pragma unroll
    for (int ni = 0; ni < 4; ++ni) {
      int row = wn + ni * 16 + fr;
      bfr[ni] = *(const bf16x8*)&Bs[cur][row * 32 + ((fg ^ (fr & 3)) * 8)];
    }
#pragma unroll
    for (int mi = 0; mi < 4; ++mi)
#pragma unroll
      for (int ni = 0; ni < 4; ++ni)
        acc[mi][ni] = mfma16(af[mi], bfr[ni], acc[mi][ni]);
    asm volatile("s_waitcnt vmcnt(0)" ::: "memory");
    __builtin_amdgcn_s_barrier();
  }

  const int frow = fg * 4;
#pragma unroll
  for (int mi = 0; mi < 4; ++mi)
#pragma unroll
    for (int ni = 0; ni < 4; ++ni) {
      int n = n0 + wn + ni * 16 + fr;
#pragma unroll
      for (int i = 0; i < 4; ++i) {
        int r = m0 + wm + mi * 16 + frow + i;
        O[(size_t)r * 1024 + n] = acc[mi][ni][i];
      }
    }
}

// ---------------- flash attention v4 ---------------------------------------
// 8 waves (512 thr), QBLK=128, KVBLK=64. Swapped QK^T (k lane-local).
// VALU diet: raw v_exp_f32 via builtin; denominator via P*ones MFMA
// (lsum C/D rows == po rows -> zero epilogue shuffles); unroll-2 for
// compile-time dbuf index; rcp epilogue.
__global__ __launch_bounds__(512, 6)
void attn_fwd(const unsigned short* __restrict__ Q,
              const unsigned short* __restrict__ K,
              const unsigned short* __restrict__ Vt,
              const unsigned long long* __restrict__ Mbits,
              unsigned short* __restrict__ Oa) {
  __shared__ __align__(16) unsigned short Ks[2][64 * 64];
  __shared__ __align__(16) unsigned short Vs[2][64 * 64];
  __shared__ __align__(16) unsigned short Ps[8][16][72];

  const int bid0 = blockIdx.x;
  const int wg = (bid0 & 7) * 128 + (bid0 >> 3);   // XCD swizzle (1024%8==0)
  const int qt = wg & 15;
  const int h = (wg >> 4) & 15;
  const int b = wg >> 8;
  const int tid = threadIdx.x;
  const int lane = tid & 63;
  const int wave = tid >> 6;
  const int fr = lane & 15;
  const int fg = lane >> 4;
  const int frow = fg * 4;

  const unsigned short* Qb = Q + (size_t)(b * 16 + h) * (2048 * 64);
  const unsigned short* Kb = K + (size_t)(b * 16 + h) * (2048 * 64);
  const unsigned short* Vb = Vt + (size_t)(b * 16 + h) * (64 * 2048);

  const int q0 = qt * 128 + wave * 16;

  bf16x8 qf0 = *(const bf16x8*)&Qb[(q0 + fr) * 64 + fg * 8];
  bf16x8 qf1 = *(const bf16x8*)&Qb[(q0 + fr) * 64 + 32 + fg * 8];

  // constant all-ones B-fragment for the denominator MFMA
  bf16x8 onesf;
#pragma unroll
  for (int j = 0; j < 8; ++j) onesf[j] = (__bf16)1.0f;

  f4 po[4];
#pragma unroll
  for (int nd = 0; nd < 4; ++nd) po[nd] = (f4){0.f, 0.f, 0.f, 0.f};
  f4 lsum = (f4){0.f, 0.f, 0.f, 0.f};   // lsum[i] = denom for q=frow+i

  const int krow0 = lane >> 3;
  const int kslot = (lane & 7) ^ (krow0 & 7);
  const unsigned short* kg = Kb + (size_t)(wave * 8 + krow0) * 64 + kslot * 8;
  const unsigned short* vg = Vb + (size_t)(wave * 8 + krow0) * 2048 + kslot * 8;

  const unsigned long long* mrow = Mbits + (size_t)(b * 2048 + q0 + fr) * 32;

  gload16(kg, &Ks[0][wave * 512]);
  gload16(vg, &Vs[0][wave * 512]);
  asm volatile("s_waitcnt vmcnt(0)" ::: "memory");
  __builtin_amdgcn_s_barrier();

#pragma unroll 2
  for (int kt = 0; kt < 32; ++kt) {
    const int cur = kt & 1;

    unsigned long long w = mrow[kt];

    if (kt < 31) {
      const int nxt = cur ^ 1;
      gload16(kg + (size_t)(kt + 1) * 4096, &Ks[nxt][wave * 512]);
      gload16(vg + (kt + 1) * 64, &Vs[nxt][wave * 512]);
    }

    // S^T = K x Q^T : sf[nf][i] = S[q0+fr][kt*64 + nf*16 + fg*4 + i]
    f4 sf[4];
    __builtin_amdgcn_s_setprio(1);
#pragma unroll
    for (int nf = 0; nf < 4; ++nf) {
      int krow = nf * 16 + fr;
      int sw = krow & 7;
      bf16x8 kf0 = *(const bf16x8*)&Ks[cur][krow * 64 + ((fg ^ sw) * 8)];
      bf16x8 kf1 = *(const bf16x8*)&Ks[cur][krow * 64 + (((4 + fg) ^ sw) * 8)];
      f4 a = (f4){0.f, 0.f, 0.f, 0.f};
      a = mfma16(kf0, qf0, a);
      a = mfma16(kf1, qf1, a);
      sf[nf] = a;
    }
    __builtin_amdgcn_s_setprio(0);

    // p = mask ? exp2(s) : 0   (scale pre-folded into Q; no online max)
    unsigned lo = (unsigned)w >> (fg * 4);
    unsigned hi = (unsigned)(w >> 32) >> (fg * 4);
#pragma unroll
    for (int nf = 0; nf < 4; ++nf) {
      unsigned wsel = (nf & 2) ? hi : lo;
      float p0 = __builtin_amdgcn_exp2f(sf[nf][0]);
      float p1 = __builtin_amdgcn_exp2f(sf[nf][1]);
      float p2 = __builtin_amdgcn_exp2f(sf[nf][2]);
      float p3 = __builtin_amdgcn_exp2f(sf[nf][3]);
      const int sh = (nf & 1) << 4;
      if (!((wsel >> (sh + 0)) & 1)) p0 = 0.f;
      if (!((wsel >> (sh + 1)) & 1)) p1 = 0.f;
      if (!((wsel >> (sh + 2)) & 1)) p2 = 0.f;
      if (!((wsel >> (sh + 3)) & 1)) p3 = 0.f;
      bf16x4 pk = { (__bf16)p0, (__bf16)p1, (__bf16)p2, (__bf16)p3 };
      *(bf16x4*)&Ps[wave][fr][nf * 16 + frow] = pk;
    }
    bf16x8 pf0 = *(const bf16x8*)&Ps[wave][fr][fg * 8];
    bf16x8 pf1 = *(const bf16x8*)&Ps[wave][fr][32 + fg * 8];

    __builtin_amdgcn_s_setprio(1);
    // denominator rides the idle MFMA pipe; D rows = po rows, no shuffles
    lsum = mfma16(pf0, onesf, lsum);
    lsum = mfma16(pf1, onesf, lsum);
#pragma unroll
    for (int nd = 0; nd < 4; ++nd) {
      int vrow = nd * 16 + fr;
      int sw = vrow & 7;
      bf16x8 vf0 = *(const bf16x8*)&Vs[cur][vrow * 64 + ((fg ^ sw) * 8)];
      bf16x8 vf1 = *(const bf16x8*)&Vs[cur][vrow * 64 + (((4 + fg) ^ sw) * 8)];
      po[nd] = mfma16(pf0, vf0, po[nd]);
      po[nd] = mfma16(pf1, vf1, po[nd]);
    }
    __builtin_amdgcn_s_setprio(0);

    asm volatile("s_waitcnt vmcnt(0)" ::: "memory");
    __builtin_amdgcn_s_barrier();
  }

  // epilogue: out[b][t][h*64+d] = po / lsum (row mappings already match)
  float inv[4];
#pragma unroll
  for (int i = 0; i < 4; ++i) inv[i] = __builtin_amdgcn_rcpf(lsum[i]);
#pragma unroll
  for (int nd = 0; nd < 4; ++nd) {
    int col = h * 64 + nd * 16 + fr;
#pragma unroll
    for (int i = 0; i < 4; ++i) {
      int r = b * 2048 + q0 + frow + i;
      float o = po[nd][i] * inv[i];
      Oa[(size_t)r * 1024 + col] = f2bf(o);
    }
  }
}

// ---------------------------------------------------------------------------
extern "C" void kernel_launch(void* const* d_in, const int* in_sizes, int n_in,
                              void* d_out, int out_size, void* d_ws, size_t ws_size,
                              hipStream_t stream) {
  const float* x = (const float*)d_in[0];
  const int* mask = (const int*)d_in[1];
  const float* Wq = (const float*)d_in[2];
  const float* Wk = (const float*)d_in[3];
  const float* Wv = (const float*)d_in[4];
  const float* Wo = (const float*)d_in[5];
  float* out = (float*)d_out;
  char* ws = (char*)d_ws;

  float* cosT = (float*)(ws + 0x0);
  float* sinT = (float*)(ws + 0x80000);
  float* scT  = (float*)(ws + 0x100000);
  float* iscT = (float*)(ws + 0x180000);
  // mask bits (2MB) ALIAS the tables region: written after gemm_qkv is done
  unsigned long long* mbits = (unsigned long long*)(ws + 0x0);
  unsigned short* xb  = (unsigned short*)(ws + 0x200000);   // 16MB
  unsigned short* wqb = (unsigned short*)(ws + 0x1200000);  // 2MB each
  unsigned short* wkb = (unsigned short*)(ws + 0x1400000);
  unsigned short* wvb = (unsigned short*)(ws + 0x1600000);
  unsigned short* wob = (unsigned short*)(ws + 0x1800000);
  unsigned short* Qb  = (unsigned short*)(ws + 0x1A00000);  // 16MB each
  unsigned short* Kb  = (unsigned short*)(ws + 0x2A00000);
  unsigned short* Vtb = (unsigned short*)(ws + 0x3A00000);
  unsigned short* Aob = (unsigned short*)(ws + 0x4A00000);  // ends 0x5A00000

  prep_tables<<<(T_ * (D_ / 2) + 255) / 256, 256, 0, stream>>>(cosT, sinT, scT, iscT);
  cvt_all<<<8192 + 4096, 256, 0, stream>>>(x, Wq, Wk, Wv, Wo,
                                           xb, wqb, wkb, wvb, wob);

  dim3 gq(C_ / 128, M_ / 128, 3);   // (8, 64, 3)
  gemm_qkv<<<gq, 256, 0, stream>>>(xb, wqb, wkb, wvb, Qb, Kb, Vtb,
                                   cosT, sinT, scT, iscT);

  // pack mask AFTER gemm_qkv (mbits aliases the then-dead RoPE tables)
  pack_mask<<<16384, 256, 0, stream>>>(mask, mbits);

  attn_fwd<<<B_ * H_ * (T_ / 128), 512, 0, stream>>>(Qb, Kb, Vtb, mbits, Aob);

  dim3 go(C_ / 128, M_ / 128);      // (8, 64)
  gemm_out<<<go, 256, 0, stream>>>(Aob, wob, out);
}